// Round 12
// baseline (208.532 us; speedup 1.0000x reference)
//
#include <hip/hip_runtime.h>
#include <hip/hip_bf16.h>

#define AS1 __attribute__((address_space(1)))
#define AS3 __attribute__((address_space(3)))

typedef __attribute__((ext_vector_type(4))) float floatx4;
typedef __attribute__((ext_vector_type(8))) short bf16x8;
typedef unsigned short u16;
typedef unsigned int u32;

// ---- bf16 helpers ----
__device__ __forceinline__ u16 f2b(float f) {  // RNE
  u32 u = __builtin_bit_cast(u32, f);
  u += 0x7fffu + ((u >> 16) & 1u);
  return (u16)(u >> 16);
}
__device__ __forceinline__ u32 pk2(float lo, float hi) {
  __hip_bfloat162 h = __float22bfloat162_rn(float2{lo, hi});
  u32 u;
  __builtin_memcpy(&u, &h, 4);
  return u;
}
__device__ __forceinline__ bf16x8 cvt8(float4 a, float4 b) {
  uint4 u{pk2(a.x, a.y), pk2(a.z, a.w), pk2(b.x, b.y), pk2(b.z, b.w)};
  return __builtin_bit_cast(bf16x8, u);
}

__device__ __forceinline__ void gld16(const void* g, AS3 u32* l) {
  __builtin_amdgcn_global_load_lds((const AS1 u32*)(const AS1 void*)g, l, 16,
                                   0, 0);
}

// Q is pre-scaled by 1/sqrt(64) * log2(e) so attention softmax is
// exp2(st - 10*log2(e)) with no per-element multiply.
#define QSCALE 0.18033688011112042f  // 0.125 * log2(e)
#define QSHIFT 14.4269504088896f     // 10 * log2(e)

// ================= bulk f32 -> bf16 conversion (x + 4 weights) ==============
__global__ __launch_bounds__(256) void cvt_all(
    const float* __restrict__ x, const float* __restrict__ wq,
    const float* __restrict__ wk, const float* __restrict__ wv,
    const float* __restrict__ wo, u16* __restrict__ xb, u16* __restrict__ wqb,
    u16* __restrict__ wkb, u16* __restrict__ wvb, u16* __restrict__ wob) {
  const int i = blockIdx.x * 256 + threadIdx.x;  // handles 8 elems
  const float* src;
  u16* dst;
  int off;
  if (i < 524288) {
    src = x; dst = xb; off = i;
  } else {
    const int j = i - 524288;
    const int wsel = j >> 17;
    off = j & 131071;
    src = (wsel == 0) ? wq : (wsel == 1) ? wk : (wsel == 2) ? wv : wo;
    dst = (wsel == 0) ? wqb : (wsel == 1) ? wkb : (wsel == 2) ? wvb : wob;
  }
  const float4* p = (const float4*)(src + (size_t)off * 8);
  *(bf16x8*)(dst + (size_t)off * 8) = cvt8(p[0], p[1]);
}

// ====== bf16 128x128 GEMM mainloop (m97 pattern): global_load_lds w=16 ======
__device__ __forceinline__ void gemm_bf16(const u16* __restrict__ A,
                                          const u16* __restrict__ B, short* sA,
                                          short* sB, floatx4 acc[4][4]) {
  const int tid = threadIdx.x;
  const int lane = tid & 63;
  const int w = tid >> 6;
  const int l15 = lane & 15, quad = lane >> 4;
  const int wm = w >> 1, wn = w & 1;

  const u16* ga = A + ((size_t)(w * 32 + (lane >> 2))) * 1024 + (lane & 3) * 8;
  const u16* gb = B + ((size_t)(w * 32 + (lane >> 2))) * 1024 + (lane & 3) * 8;
  AS3 u32* la = (AS3 u32*)(AS3 short*)sA + w * 512;
  AS3 u32* lb = (AS3 u32*)(AS3 short*)sB + w * 512;

  for (int kt = 0; kt < 32; ++kt) {
    __syncthreads();
    gld16(ga, la);
    gld16(ga + (size_t)16 * 1024, la + 256);
    gld16(gb, lb);
    gld16(gb + (size_t)16 * 1024, lb + 256);
    ga += 32;
    gb += 32;
    __syncthreads();

    bf16x8 af[4], bfr[4];
#pragma unroll
    for (int mc = 0; mc < 4; ++mc)
      af[mc] = *(const bf16x8*)&sA[(wm * 64 + mc * 16 + l15) * 32 + quad * 8];
#pragma unroll
    for (int nc = 0; nc < 4; ++nc)
      bfr[nc] = *(const bf16x8*)&sB[(wn * 64 + nc * 16 + l15) * 32 + quad * 8];
#pragma unroll
    for (int mc = 0; mc < 4; ++mc)
#pragma unroll
      for (int nc = 0; nc < 4; ++nc)
        acc[mc][nc] = __builtin_amdgcn_mfma_f32_16x16x32_bf16(
            af[mc], bfr[nc], acc[mc][nc], 0, 0, 0);
  }
}

// ---------------- QKV epilogue (shared by both paths) -----------------------
__device__ __forceinline__ void qkv_epilogue(floatx4 acc[4][4], int m0, int nb,
                                             int sel, u16* __restrict__ Q,
                                             u16* __restrict__ K,
                                             u16* __restrict__ Vt) {
  const int tid = threadIdx.x;
  const int lane = tid & 63, w = tid >> 6;
  const int l15 = lane & 15, quad = lane >> 4;
  const int wm = w >> 1, wn = w & 1;
#pragma unroll
  for (int mc = 0; mc < 4; ++mc) {
#pragma unroll
    for (int nc = 0; nc < 4; ++nc) {
      const int nn = nb + wn * 64 + nc * 16 + l15;
      const int h = nn >> 6, d = nn & 63;
#pragma unroll
      for (int r = 0; r < 4; ++r) {
        const int m = m0 + wm * 64 + mc * 16 + quad * 4 + r;
        const int b = m >> 11, s = m & 2047;
        const int bh = b * 16 + h;
        float av = acc[mc][nc][r];
        if (sel == 0) av *= QSCALE;  // fold softmax scale into Q
        const u16 v = f2b(av);
        if (sel == 0)
          Q[((size_t)bh * 2048 + s) * 64 + d] = v;
        else if (sel == 1)
          K[((size_t)bh * 2048 + s) * 64 + d] = v;
        else
          Vt[((size_t)bh * 64 + d) * 2048 + s] = v;
      }
    }
  }
}

// XCD-aware bijective work remap (T1): 768 blocks = 8 XCDs x 96. Hardware
// round-robins linear block id across XCDs; remapping work so XCD r owns
// by in [3r, 3r+3) shrinks the per-XCD W-panel footprint 6MB -> 768KB (L2-fit).
__global__ __launch_bounds__(256) void qkv_gemm_b(
    const u16* __restrict__ xb, const u16* __restrict__ Wqb,
    const u16* __restrict__ Wkb, const u16* __restrict__ Wvb,
    u16* __restrict__ Q, u16* __restrict__ K, u16* __restrict__ Vt) {
  __shared__ __align__(16) short smem[2 * 128 * 32];
  const int lin = blockIdx.y * 32 + blockIdx.x;   // 0..767
  const int swz = (lin & 7) * 96 + (lin >> 3);    // bijective (768 = 8*96)
  const int m0 = (swz & 31) * 128;
  const int by = swz >> 5;
  const int sel = by >> 3;
  const int nb = (by & 7) * 128;
  const u16* W = (sel == 0) ? Wqb : (sel == 1) ? Wkb : Wvb;

  floatx4 acc[4][4];
#pragma unroll
  for (int i = 0; i < 4; i++)
#pragma unroll
    for (int j = 0; j < 4; j++) acc[i][j] = (floatx4)0.0f;
  gemm_bf16(xb + (size_t)m0 * 1024, W + (size_t)nb * 1024, smem,
            smem + 128 * 32, acc);
  qkv_epilogue(acc, m0, nb, sel, Q, K, Vt);
}

// ---- out projection: 128x64 tiles, grid 512 (XCD-swizzled: 512 = 8*64) ----
__global__ __launch_bounds__(256) void out_gemm_b(const u16* __restrict__ ctx,
                                                  const u16* __restrict__ Wob,
                                                  const float* __restrict__ bo,
                                                  float* __restrict__ out) {
  __shared__ __align__(16) short smem[128 * 32 + 64 * 32];
  const int tid = threadIdx.x;
  const int lane = tid & 63, w = tid >> 6;
  const int l15 = lane & 15, quad = lane >> 4;
  const int lin = blockIdx.y * 32 + blockIdx.x;  // 0..511
  const int swz = (lin & 7) * 64 + (lin >> 3);   // bijective (512 = 8*64)
  const int m0 = (swz & 31) * 128;
  const int n0 = (swz >> 5) * 64;
  short* sA = smem;
  short* sB = smem + 128 * 32;

  const u16* ga = ctx + ((size_t)(m0 + w * 32 + (lane >> 2))) * 1024 +
                  (lane & 3) * 8;
  const u16* gb = Wob + ((size_t)(n0 + w * 16 + (lane >> 2))) * 1024 +
                  (lane & 3) * 8;
  AS3 u32* la = (AS3 u32*)(AS3 short*)sA + w * 512;
  AS3 u32* lb = (AS3 u32*)(AS3 short*)sB + w * 256;

  floatx4 acc[2][4];
#pragma unroll
  for (int i = 0; i < 2; i++)
#pragma unroll
    for (int j = 0; j < 4; j++) acc[i][j] = (floatx4)0.0f;

  for (int kt = 0; kt < 32; ++kt) {
    __syncthreads();
    gld16(ga, la);
    gld16(ga + (size_t)16 * 1024, la + 256);
    gld16(gb, lb);
    ga += 32;
    gb += 32;
    __syncthreads();

    bf16x8 af[2], bfr[4];
#pragma unroll
    for (int mc = 0; mc < 2; ++mc)
      af[mc] = *(const bf16x8*)&sA[(w * 32 + mc * 16 + l15) * 32 + quad * 8];
#pragma unroll
    for (int nc = 0; nc < 4; ++nc)
      bfr[nc] = *(const bf16x8*)&sB[(nc * 16 + l15) * 32 + quad * 8];
#pragma unroll
    for (int mc = 0; mc < 2; ++mc)
#pragma unroll
      for (int nc = 0; nc < 4; ++nc)
        acc[mc][nc] = __builtin_amdgcn_mfma_f32_16x16x32_bf16(
            af[mc], bfr[nc], acc[mc][nc], 0, 0, 0);
  }

#pragma unroll
  for (int mc = 0; mc < 2; ++mc)
#pragma unroll
    for (int nc = 0; nc < 4; ++nc) {
      const int n = n0 + nc * 16 + l15;
      const float bias = bo[n];
#pragma unroll
      for (int r = 0; r < 4; ++r) {
        const int m = m0 + w * 32 + mc * 16 + quad * 4 + r;
        out[(size_t)m * 1024 + n] = acc[mc][nc][r] + bias;
      }
    }
}

// ============ Fallback f32-staging 128x128 GEMM (round-12, verified) ========
template <bool F32A>
__device__ __forceinline__ void gemm128(const void* __restrict__ A,
                                        const float* __restrict__ B, short* sA,
                                        short* sB, floatx4 acc[4][4]) {
  const int tid = threadIdx.x;
  const int lane = tid & 63;
  const int w = tid >> 6;
  const int l15 = lane & 15, quad = lane >> 4;
  const int wm = w >> 1, wn = w & 1;
  const int srow = tid >> 1;
  const int scb = (tid & 1) * 16;

  float4 pa[4], pb[4];
  int4 pa16[2];
  if constexpr (F32A) {
    const float* ap = (const float*)A + (size_t)srow * 1024 + scb;
    pa[0] = ((const float4*)ap)[0]; pa[1] = ((const float4*)ap)[1];
    pa[2] = ((const float4*)ap)[2]; pa[3] = ((const float4*)ap)[3];
  } else {
    const u16* ap = (const u16*)A + (size_t)srow * 1024 + scb;
    pa16[0] = ((const int4*)ap)[0]; pa16[1] = ((const int4*)ap)[1];
  }
  {
    const float* bp = B + (size_t)srow * 1024 + scb;
    pb[0] = ((const float4*)bp)[0]; pb[1] = ((const float4*)bp)[1];
    pb[2] = ((const float4*)bp)[2]; pb[3] = ((const float4*)bp)[3];
  }

  for (int kt = 0; kt < 32; ++kt) {
    __syncthreads();
    if constexpr (F32A) {
      *(bf16x8*)&sA[srow * 40 + scb] = cvt8(pa[0], pa[1]);
      *(bf16x8*)&sA[srow * 40 + scb + 8] = cvt8(pa[2], pa[3]);
    } else {
      *(int4*)&sA[srow * 40 + scb] = pa16[0];
      *(int4*)&sA[srow * 40 + scb + 8] = pa16[1];
    }
    *(bf16x8*)&sB[srow * 40 + scb] = cvt8(pb[0], pb[1]);
    *(bf16x8*)&sB[srow * 40 + scb + 8] = cvt8(pb[2], pb[3]);
    __syncthreads();

    if (kt < 31) {
      const int k0 = (kt + 1) * 32;
      if constexpr (F32A) {
        const float* ap = (const float*)A + (size_t)srow * 1024 + k0 + scb;
        pa[0] = ((const float4*)ap)[0]; pa[1] = ((const float4*)ap)[1];
        pa[2] = ((const float4*)ap)[2]; pa[3] = ((const float4*)ap)[3];
      } else {
        const u16* ap = (const u16*)A + (size_t)srow * 1024 + k0 + scb;
        pa16[0] = ((const int4*)ap)[0]; pa16[1] = ((const int4*)ap)[1];
      }
      const float* bp = B + (size_t)srow * 1024 + k0 + scb;
      pb[0] = ((const float4*)bp)[0]; pb[1] = ((const float4*)bp)[1];
      pb[2] = ((const float4*)bp)[2]; pb[3] = ((const float4*)bp)[3];
    }

    bf16x8 af[4], bfr[4];
#pragma unroll
    for (int mc = 0; mc < 4; ++mc)
      af[mc] = *(const bf16x8*)&sA[(wm * 64 + mc * 16 + l15) * 40 + quad * 8];
#pragma unroll
    for (int nc = 0; nc < 4; ++nc)
      bfr[nc] = *(const bf16x8*)&sB[(wn * 64 + nc * 16 + l15) * 40 + quad * 8];
#pragma unroll
    for (int mc = 0; mc < 4; ++mc)
#pragma unroll
      for (int nc = 0; nc < 4; ++nc)
        acc[mc][nc] = __builtin_amdgcn_mfma_f32_16x16x32_bf16(
            af[mc], bfr[nc], acc[mc][nc], 0, 0, 0);
  }
}

__global__ __launch_bounds__(256) void qkv_gemm_f(
    const float* __restrict__ x, const float* __restrict__ Wq,
    const float* __restrict__ Wk, const float* __restrict__ Wv,
    u16* __restrict__ Q, u16* __restrict__ K, u16* __restrict__ Vt) {
  __shared__ __align__(16) short smem[2 * 128 * 40];
  const int m0 = blockIdx.x * 128;
  const int by = blockIdx.y;
  const int sel = by >> 3;
  const int nb = (by & 7) * 128;
  const float* W = (sel == 0) ? Wq : (sel == 1) ? Wk : Wv;

  floatx4 acc[4][4];
#pragma unroll
  for (int i = 0; i < 4; i++)
#pragma unroll
    for (int j = 0; j < 4; j++) acc[i][j] = (floatx4)0.0f;
  gemm128<true>((const void*)(x + (size_t)m0 * 1024), W + (size_t)nb * 1024,
                smem, smem + 128 * 40, acc);
  qkv_epilogue(acc, m0, nb, sel, Q, K, Vt);
}

__global__ __launch_bounds__(256) void out_gemm_f(const u16* __restrict__ ctx,
                                                  const float* __restrict__ Wo,
                                                  const float* __restrict__ bo,
                                                  float* __restrict__ out) {
  __shared__ __align__(16) short smem[2 * 128 * 40];
  const int tid = threadIdx.x;
  const int lane = tid & 63, w = tid >> 6;
  const int l15 = lane & 15, quad = lane >> 4;
  const int wm = w >> 1, wn = w & 1;
  const int m0 = blockIdx.x * 128;
  const int n0 = blockIdx.y * 128;

  floatx4 acc[4][4];
#pragma unroll
  for (int i = 0; i < 4; i++)
#pragma unroll
    for (int j = 0; j < 4; j++) acc[i][j] = (floatx4)0.0f;
  gemm128<false>((const void*)(ctx + (size_t)m0 * 1024),
                 Wo + (size_t)n0 * 1024, smem, smem + 128 * 40, acc);

#pragma unroll
  for (int mc = 0; mc < 4; ++mc)
#pragma unroll
    for (int nc = 0; nc < 4; ++nc) {
      const int n = n0 + wn * 64 + nc * 16 + l15;
      const float bias = bo[n];
#pragma unroll
      for (int r = 0; r < 4; ++r) {
        const int m = m0 + wm * 64 + mc * 16 + quad * 4 + r;
        out[(size_t)m * 1024 + n] = acc[mc][nc][r] + bias;
      }
    }
}

// ======== per-chunk attention tile (R3/R5 verified paths, no setprio) =======
// CLEAN=true : full 128-key tile, no masks, 2-deep SW pipeline.
// CLEAN=false: diagonal tile with per-kp break + causal masks.
template <bool CLEAN>
__device__ __forceinline__ void attn_tile(const u16* __restrict__ sKb,
                                          const u16* __restrict__ sVb,
                                          const int l15, const int quad,
                                          const int jbase, const int wrow,
                                          const bf16x8 aQ0, const bf16x8 aQ1,
                                          floatx4 (&acc)[4], floatx4& lsv) {
  if constexpr (CLEAN) {
    bf16x8 ka[2][4];
    uint2 va[2][8];
#pragma unroll
    for (int u = 0; u < 4; ++u) {
      const u16* kp0 = sKb + l15 * 72 + quad * 8;
      ka[0][u] = *(const bf16x8*)(kp0 + (u >> 1) * (16 * 72) + (u & 1) * 32);
    }
#pragma unroll
    for (int dt = 0; dt < 4; ++dt) {
      const u16* vp = sVb + (dt * 16 + l15) * 136 + quad * 4;
      va[0][2 * dt] = *(const uint2*)(vp);
      va[0][2 * dt + 1] = *(const uint2*)(vp + 16);
    }
#pragma unroll
    for (int kp = 0; kp < 4; ++kp) {
      const int pc = kp & 1, pn = (kp + 1) & 1;
      if (kp < 3) {
        const u16* kp1 = sKb + ((kp + 1) * 32 + l15) * 72 + quad * 8;
#pragma unroll
        for (int u = 0; u < 4; ++u)
          ka[pn][u] =
              *(const bf16x8*)(kp1 + (u >> 1) * (16 * 72) + (u & 1) * 32);
#pragma unroll
        for (int dt = 0; dt < 4; ++dt) {
          const u16* vp =
              sVb + (dt * 16 + l15) * 136 + (kp + 1) * 32 + quad * 4;
          va[pn][2 * dt] = *(const uint2*)(vp);
          va[pn][2 * dt + 1] = *(const uint2*)(vp + 16);
        }
      }
      floatx4 st0 = (floatx4)0.0f, st1 = (floatx4)0.0f;
      st0 = __builtin_amdgcn_mfma_f32_16x16x32_bf16(ka[pc][0], aQ0, st0, 0, 0,
                                                    0);
      st1 = __builtin_amdgcn_mfma_f32_16x16x32_bf16(ka[pc][2], aQ0, st1, 0, 0,
                                                    0);
      st0 = __builtin_amdgcn_mfma_f32_16x16x32_bf16(ka[pc][1], aQ1, st0, 0, 0,
                                                    0);
      st1 = __builtin_amdgcn_mfma_f32_16x16x32_bf16(ka[pc][3], aQ1, st1, 0, 0,
                                                    0);
      float p0[4], p1[4];
#pragma unroll
      for (int r = 0; r < 4; ++r) {
        p0[r] = __builtin_amdgcn_exp2f(st0[r] - QSHIFT);
        p1[r] = __builtin_amdgcn_exp2f(st1[r] - QSHIFT);
      }
#pragma unroll
      for (int r = 0; r < 4; ++r) lsv[r] += p0[r] + p1[r];
      uint4 pfu{pk2(p0[0], p0[1]), pk2(p0[2], p0[3]), pk2(p1[0], p1[1]),
                pk2(p1[2], p1[3])};
      const bf16x8 pf8 = __builtin_bit_cast(bf16x8, pfu);
#pragma unroll
      for (int dt = 0; dt < 4; ++dt) {
        uint4 avu{va[pc][2 * dt].x, va[pc][2 * dt].y, va[pc][2 * dt + 1].x,
                  va[pc][2 * dt + 1].y};
        bf16x8 av8 = __builtin_bit_cast(bf16x8, avu);
        acc[dt] = __builtin_amdgcn_mfma_f32_16x16x32_bf16(av8, pf8, acc[dt],
                                                          0, 0, 0);
      }
    }
  } else {
#pragma unroll 2
    for (int kp = 0; kp < 4; ++kp) {
      const int kbase = jbase + kp * 32;
      if (kbase > wrow + 15) break;  // wave-uniform

      const u16* kr0 = sKb + (kp * 32 + l15) * 72 + quad * 8;
      bf16x8 ak00 = *(const bf16x8*)(kr0);
      bf16x8 ak01 = *(const bf16x8*)(kr0 + 32);
      floatx4 st0 = (floatx4)0.0f;
      st0 = __builtin_amdgcn_mfma_f32_16x16x32_bf16(ak00, aQ0, st0, 0, 0, 0);
      st0 = __builtin_amdgcn_mfma_f32_16x16x32_bf16(ak01, aQ1, st0, 0, 0, 0);

      const bool have1 = (kbase + 16 <= wrow + 15);  // wave-uniform
      floatx4 st1 = (floatx4)0.0f;
      if (have1) {
        const u16* kr1 = kr0 + 16 * 72;
        bf16x8 ak10 = *(const bf16x8*)(kr1);
        bf16x8 ak11 = *(const bf16x8*)(kr1 + 32);
        st1 = __builtin_amdgcn_mfma_f32_16x16x32_bf16(ak10, aQ0, st1, 0, 0, 0);
        st1 = __builtin_amdgcn_mfma_f32_16x16x32_bf16(ak11, aQ1, st1, 0, 0, 0);
      }

      float p0[4], p1[4];
      const bool m0b = (kbase + 15 > wrow);
#pragma unroll
      for (int r = 0; r < 4; ++r) {
        float t = st0[r] - QSHIFT;
        if (m0b && (kbase + quad * 4 + r > wrow + l15)) t = -1e30f;
        p0[r] = __builtin_amdgcn_exp2f(t);
      }
      if (have1) {
        const bool m1b = (kbase + 31 > wrow);
#pragma unroll
        for (int r = 0; r < 4; ++r) {
          float t = st1[r] - QSHIFT;
          if (m1b && (kbase + 16 + quad * 4 + r > wrow + l15)) t = -1e30f;
          p1[r] = __builtin_amdgcn_exp2f(t);
        }
      } else {
        p1[0] = p1[1] = p1[2] = p1[3] = 0.0f;
      }
#pragma unroll
      for (int r = 0; r < 4; ++r) lsv[r] += p0[r] + p1[r];

      uint4 pfu{pk2(p0[0], p0[1]), pk2(p0[2], p0[3]), pk2(p1[0], p1[1]),
                pk2(p1[2], p1[3])};
      const bf16x8 pf8 = __builtin_bit_cast(bf16x8, pfu);

#pragma unroll
      for (int dt = 0; dt < 4; ++dt) {
        const u16* vp = sVb + (dt * 16 + l15) * 136 + kp * 32 + quad * 4;
        uint2 v0 = *(const uint2*)(vp);
        uint2 v1 = *(const uint2*)(vp + 16);  // p1=0 past diagonal
        uint4 avu{v0.x, v0.y, v1.x, v1.y};
        bf16x8 av8 = __builtin_bit_cast(bf16x8, avu);
        acc[dt] = __builtin_amdgcn_mfma_f32_16x16x32_bf16(av8, pf8, acc[dt],
                                                          0, 0, 0);
      }
    }
  }
}

// --------- per-chunk output write (round-3 epilogue, parameterized) ---------
__device__ __forceinline__ void attn_write(u16* tw, const floatx4 (&acc)[4],
                                           const floatx4 lsv, const int l15,
                                           const int quad, const int wrow,
                                           const int b, const int h,
                                           u16* __restrict__ ctx) {
  float lsum = (lsv[0] + lsv[1]) + (lsv[2] + lsv[3]);
  lsum += __shfl_xor(lsum, 16, 64);
  lsum += __shfl_xor(lsum, 32, 64);
  const float inv = 1.0f / lsum;
#pragma unroll
  for (int dt = 0; dt < 4; ++dt) {
    uint2 o2{pk2(acc[dt][0] * inv, acc[dt][1] * inv),
             pk2(acc[dt][2] * inv, acc[dt][3] * inv)};
    *(uint2*)&tw[l15 * 72 + dt * 16 + quad * 4] = o2;
  }
  // in-wave write->read DS ordering (wave-exclusive region)
  bf16x8 o0 = *(const bf16x8*)&tw[l15 * 72 + quad * 16];
  bf16x8 o1 = *(const bf16x8*)&tw[l15 * 72 + quad * 16 + 8];
  u16* cp =
      ctx + ((size_t)(b * 2048 + wrow + l15)) * 1024 + h * 64 + quad * 16;
  *(bf16x8*)cp = o0;
  *(bf16x8*)(cp + 8) = o1;
}

// ====== Kernel: causal flash attention (dual-chunk shared K/V stream) =======
// R5/R11 structure verbatim (verified optimum: attn ~60us): 256 blocks =
// 8 pairs x 32 bh (bid&31 = bh keeps XCD affinity; 1 block/CU). Chunks
// A=15-pr and B=pr (128 q each, SAME bh) share one tile loop 0..cA; per
// staged tile the verified R3 tile function runs for A and (while jb<=cB)
// for B. Compute units/block = 17 for every pr (balanced); staged tiles
// 16-pr. Double-buffered LDS, 1 barrier/tile; fixed-shift softmax;
// Q pre-scaled by 0.125*log2e.
__global__ __launch_bounds__(512, 2) void attn_kernel(
    const u16* __restrict__ Q, const u16* __restrict__ K,
    const u16* __restrict__ Vt, u16* __restrict__ ctx) {
  const int bid = blockIdx.x;
  const int pr = bid >> 5;  // pair index 0..7
  const int bh = bid & 31;
  const int tid = threadIdx.x;
  const int w = tid >> 6;  // 0..7
  const int lane = tid & 63;
  const int l15 = lane & 15;
  const int quad = lane >> 4;

  constexpr int KE = 128 * 72;  // u16 elems of K region
  constexpr int VE = 64 * 136;  // u16 elems of V region
  constexpr int BUF = KE + VE;  // 35840 B per buffer
  __shared__ __align__(16) u16 lds[2 * BUF];

  const int kr = tid >> 2, kc = (tid & 3) * 16;  // K staging (512 thr)
  const int vd = tid >> 3, vc = (tid & 7) * 16;  // V staging
  const int b = bh >> 4, h = bh & 15;

  const u16* Kg = K + (size_t)bh * 2048 * 64;
  const u16* Vg = Vt + (size_t)bh * 64 * 2048;

  const int cA = 15 - pr, cB = pr;
  const int wrowA = cA * 128 + w * 16;
  const int wrowB = cB * 128 + w * 16;

  // Q fragments for both chunks (same bh)
  bf16x8 aQA0, aQA1, aQB0, aQB1;
  {
    const u16* qa = Q + ((size_t)bh * 2048 + wrowA + l15) * 64 + quad * 8;
    aQA0 = *(const bf16x8*)(qa);
    aQA1 = *(const bf16x8*)(qa + 32);
    const u16* qb = Q + ((size_t)bh * 2048 + wrowB + l15) * 64 + quad * 8;
    aQB0 = *(const bf16x8*)(qb);
    aQB1 = *(const bf16x8*)(qb + 32);
  }

  floatx4 accA[4], accB[4];
#pragma unroll
  for (int i = 0; i < 4; ++i) {
    accA[i] = (floatx4)0.0f;
    accB[i] = (floatx4)0.0f;
  }
  floatx4 lsvA = (floatx4)0.0f, lsvB = (floatx4)0.0f;

  // prefetch + stage tile 0 into buf0
  int4 pk[2], pv[2];
  pk[0] = *(const int4*)(Kg + (size_t)kr * 64 + kc);
  pk[1] = *(const int4*)(Kg + (size_t)kr * 64 + kc + 8);
  pv[0] = *(const int4*)(Vg + (size_t)vd * 2048 + vc);
  pv[1] = *(const int4*)(Vg + (size_t)vd * 2048 + vc + 8);
  *(int4*)&lds[kr * 72 + kc] = pk[0];
  *(int4*)&lds[kr * 72 + kc + 8] = pk[1];
  *(int4*)&lds[KE + vd * 136 + vc] = pv[0];
  *(int4*)&lds[KE + vd * 136 + vc + 8] = pv[1];
  __syncthreads();
  int cur = 0;

  for (int jb = 0; jb <= cA; ++jb) {
    const u16* sKb = lds + cur * BUF;
    const u16* sVb = sKb + KE;

    // (a) prefetch next tile's globals (lands during tile compute)
    const int jn = (jb < cA) ? (jb + 1) * 128 : -1;
    if (jn >= 0) {
      pk[0] = *(const int4*)(Kg + (size_t)(jn + kr) * 64 + kc);
      pk[1] = *(const int4*)(Kg + (size_t)(jn + kr) * 64 + kc + 8);
      pv[0] = *(const int4*)(Vg + (size_t)vd * 2048 + jn + vc);
      pv[1] = *(const int4*)(Vg + (size_t)vd * 2048 + jn + vc + 8);
    }

    // (b) compute tile jb from buf[cur]: chunk A, then chunk B if active
    const int jbase = jb * 128;
    if (jb < cA)
      attn_tile<true>(sKb, sVb, l15, quad, jbase, wrowA, aQA0, aQA1, accA,
                      lsvA);
    else
      attn_tile<false>(sKb, sVb, l15, quad, jbase, wrowA, aQA0, aQA1, accA,
                       lsvA);
    if (jb < cB)
      attn_tile<true>(sKb, sVb, l15, quad, jbase, wrowB, aQB0, aQB1, accB,
                      lsvB);
    else if (jb == cB)
      attn_tile<false>(sKb, sVb, l15, quad, jbase, wrowB, aQB0, aQB1, accB,
                       lsvB);

    // (c) stage next tile into buf[cur^1] (retired at last barrier)
    if (jn >= 0) {
      u16* dK = lds + (cur ^ 1) * BUF;
      u16* dV = dK + KE;
      *(int4*)&dK[kr * 72 + kc] = pk[0];
      *(int4*)&dK[kr * 72 + kc + 8] = pk[1];
      *(int4*)&dV[vd * 136 + vc] = pv[0];
      *(int4*)&dV[vd * 136 + vc + 8] = pv[1];
    }
    // (d) one barrier per tile
    __syncthreads();
    cur ^= 1;
  }

  // ---- epilogue: both chunks; per-wave exclusive scratch in retired buf ----
  u16* tw = lds + (cur ^ 1) * BUF + (w * 16) * 72;
  attn_write(tw, accA, lsvA, l15, quad, wrowA, b, h, ctx);
  attn_write(tw, accB, lsvB, l15, quad, wrowB, b, h, ctx);
}

// ============================== launch ======================================
extern "C" void kernel_launch(void* const* d_in, const int* in_sizes, int n_in,
                              void* d_out, int out_size, void* d_ws,
                              size_t ws_size, hipStream_t stream) {
  const float* x = (const float*)d_in[0];
  const float* Wq = (const float*)d_in[1];
  const float* Wk = (const float*)d_in[2];
  const float* Wv = (const float*)d_in[3];
  const float* Wo = (const float*)d_in[4];
  const float* bo = (const float*)d_in[5];
  float* out = (float*)d_out;

  u16* Q = (u16*)d_ws;                  // 8 MB
  u16* K = Q + (size_t)4096 * 1024;     // 8 MB
  u16* Vt = K + (size_t)4096 * 1024;    // 8 MB
  u16* ctx = Vt + (size_t)4096 * 1024;  // 8 MB (shared slot with xb)

  if (ws_size >= (size_t)40 * 1024 * 1024) {
    u16* xb = ctx;  // xb consumed by qkv before attn writes ctx
    u16* Wqb = (u16*)d_ws + (size_t)16 * 1024 * 1024;  // at 32 MB
    u16* Wkb = Wqb + (size_t)1024 * 1024;
    u16* Wvb = Wkb + (size_t)1024 * 1024;
    u16* Wob = Wvb + (size_t)1024 * 1024;  // ends at 40 MB

    cvt_all<<<4096, 256, 0, stream>>>(x, Wq, Wk, Wv, Wo, xb, Wqb, Wkb, Wvb,
                                      Wob);
    qkv_gemm_b<<<dim3(32, 24), 256, 0, stream>>>(xb, Wqb, Wkb, Wvb, Q, K, Vt);
    attn_kernel<<<256, 512, 0, stream>>>(Q, K, Vt, ctx);
    out_gemm_b<<<dim3(32, 16), 256, 0, stream>>>(ctx, Wob, bo, out);
  } else {
    qkv_gemm_f<<<dim3(32, 24), 256, 0, stream>>>(x, Wq, Wk, Wv, Q, K, Vt);
    attn_kernel<<<256, 512, 0, stream>>>(Q, K, Vt, ctx);
    out_gemm_f<<<dim3(32, 8), 256, 0, stream>>>(ctx, Wo, bo, out);
  }
}

// Round 13
// 194.529 us; speedup vs baseline: 1.0720x; 1.0720x over previous
//
#include <hip/hip_runtime.h>
#include <hip/hip_bf16.h>

#define AS1 __attribute__((address_space(1)))
#define AS3 __attribute__((address_space(3)))

typedef __attribute__((ext_vector_type(4))) float floatx4;
typedef __attribute__((ext_vector_type(8))) short bf16x8;
typedef unsigned short u16;
typedef unsigned int u32;

// ---- bf16 helpers ----
__device__ __forceinline__ u16 f2b(float f) {  // RNE
  u32 u = __builtin_bit_cast(u32, f);
  u += 0x7fffu + ((u >> 16) & 1u);
  return (u16)(u >> 16);
}
__device__ __forceinline__ u32 pk2(float lo, float hi) {
  __hip_bfloat162 h = __float22bfloat162_rn(float2{lo, hi});
  u32 u;
  __builtin_memcpy(&u, &h, 4);
  return u;
}
__device__ __forceinline__ bf16x8 cvt8(float4 a, float4 b) {
  uint4 u{pk2(a.x, a.y), pk2(a.z, a.w), pk2(b.x, b.y), pk2(b.z, b.w)};
  return __builtin_bit_cast(bf16x8, u);
}

__device__ __forceinline__ void gld16(const void* g, AS3 u32* l) {
  __builtin_amdgcn_global_load_lds((const AS1 u32*)(const AS1 void*)g, l, 16,
                                   0, 0);
}

// Q is pre-scaled by 1/sqrt(64) * log2(e) so attention softmax is
// exp2(st - 10*log2(e)) with no per-element multiply.
#define QSCALE 0.18033688011112042f  // 0.125 * log2(e)
#define QSHIFT 14.4269504088896f     // 10 * log2(e)

// ================= bulk f32 -> bf16 conversion (x + 4 weights) ==============
__global__ __launch_bounds__(256) void cvt_all(
    const float* __restrict__ x, const float* __restrict__ wq,
    const float* __restrict__ wk, const float* __restrict__ wv,
    const float* __restrict__ wo, u16* __restrict__ xb, u16* __restrict__ wqb,
    u16* __restrict__ wkb, u16* __restrict__ wvb, u16* __restrict__ wob) {
  const int i = blockIdx.x * 256 + threadIdx.x;  // handles 8 elems
  const float* src;
  u16* dst;
  int off;
  if (i < 524288) {
    src = x; dst = xb; off = i;
  } else {
    const int j = i - 524288;
    const int wsel = j >> 17;
    off = j & 131071;
    src = (wsel == 0) ? wq : (wsel == 1) ? wk : (wsel == 2) ? wv : wo;
    dst = (wsel == 0) ? wqb : (wsel == 1) ? wkb : (wsel == 2) ? wvb : wob;
  }
  const float4* p = (const float4*)(src + (size_t)off * 8);
  *(bf16x8*)(dst + (size_t)off * 8) = cvt8(p[0], p[1]);
}

// ====== bf16 128x128 GEMM mainloop (m97 pattern): global_load_lds w=16 ======
__device__ __forceinline__ void gemm_bf16(const u16* __restrict__ A,
                                          const u16* __restrict__ B, short* sA,
                                          short* sB, floatx4 acc[4][4]) {
  const int tid = threadIdx.x;
  const int lane = tid & 63;
  const int w = tid >> 6;
  const int l15 = lane & 15, quad = lane >> 4;
  const int wm = w >> 1, wn = w & 1;

  const u16* ga = A + ((size_t)(w * 32 + (lane >> 2))) * 1024 + (lane & 3) * 8;
  const u16* gb = B + ((size_t)(w * 32 + (lane >> 2))) * 1024 + (lane & 3) * 8;
  AS3 u32* la = (AS3 u32*)(AS3 short*)sA + w * 512;
  AS3 u32* lb = (AS3 u32*)(AS3 short*)sB + w * 512;

  for (int kt = 0; kt < 32; ++kt) {
    __syncthreads();
    gld16(ga, la);
    gld16(ga + (size_t)16 * 1024, la + 256);
    gld16(gb, lb);
    gld16(gb + (size_t)16 * 1024, lb + 256);
    ga += 32;
    gb += 32;
    __syncthreads();

    bf16x8 af[4], bfr[4];
#pragma unroll
    for (int mc = 0; mc < 4; ++mc)
      af[mc] = *(const bf16x8*)&sA[(wm * 64 + mc * 16 + l15) * 32 + quad * 8];
#pragma unroll
    for (int nc = 0; nc < 4; ++nc)
      bfr[nc] = *(const bf16x8*)&sB[(wn * 64 + nc * 16 + l15) * 32 + quad * 8];
#pragma unroll
    for (int mc = 0; mc < 4; ++mc)
#pragma unroll
      for (int nc = 0; nc < 4; ++nc)
        acc[mc][nc] = __builtin_amdgcn_mfma_f32_16x16x32_bf16(
            af[mc], bfr[nc], acc[mc][nc], 0, 0, 0);
  }
}

// ---------------- QKV epilogue (shared by both paths) -----------------------
__device__ __forceinline__ void qkv_epilogue(floatx4 acc[4][4], int m0, int nb,
                                             int sel, u16* __restrict__ Q,
                                             u16* __restrict__ K,
                                             u16* __restrict__ Vt) {
  const int tid = threadIdx.x;
  const int lane = tid & 63, w = tid >> 6;
  const int l15 = lane & 15, quad = lane >> 4;
  const int wm = w >> 1, wn = w & 1;
#pragma unroll
  for (int mc = 0; mc < 4; ++mc) {
#pragma unroll
    for (int nc = 0; nc < 4; ++nc) {
      const int nn = nb + wn * 64 + nc * 16 + l15;
      const int h = nn >> 6, d = nn & 63;
#pragma unroll
      for (int r = 0; r < 4; ++r) {
        const int m = m0 + wm * 64 + mc * 16 + quad * 4 + r;
        const int b = m >> 11, s = m & 2047;
        const int bh = b * 16 + h;
        float av = acc[mc][nc][r];
        if (sel == 0) av *= QSCALE;  // fold softmax scale into Q
        const u16 v = f2b(av);
        if (sel == 0)
          Q[((size_t)bh * 2048 + s) * 64 + d] = v;
        else if (sel == 1)
          K[((size_t)bh * 2048 + s) * 64 + d] = v;
        else
          Vt[((size_t)bh * 64 + d) * 2048 + s] = v;
      }
    }
  }
}

__global__ __launch_bounds__(256) void qkv_gemm_b(
    const u16* __restrict__ xb, const u16* __restrict__ Wqb,
    const u16* __restrict__ Wkb, const u16* __restrict__ Wvb,
    u16* __restrict__ Q, u16* __restrict__ K, u16* __restrict__ Vt) {
  __shared__ __align__(16) short smem[2 * 128 * 32];
  const int m0 = blockIdx.x * 128;
  const int by = blockIdx.y;
  const int sel = by >> 3;
  const int nb = (by & 7) * 128;
  const u16* W = (sel == 0) ? Wqb : (sel == 1) ? Wkb : Wvb;

  floatx4 acc[4][4];
#pragma unroll
  for (int i = 0; i < 4; i++)
#pragma unroll
    for (int j = 0; j < 4; j++) acc[i][j] = (floatx4)0.0f;
  gemm_bf16(xb + (size_t)m0 * 1024, W + (size_t)nb * 1024, smem,
            smem + 128 * 32, acc);
  qkv_epilogue(acc, m0, nb, sel, Q, K, Vt);
}

// ---- out projection: 128x64 tiles -> grid 512 (2 blocks/CU, 8 waves/CU) ----
__global__ __launch_bounds__(256) void out_gemm_b(const u16* __restrict__ ctx,
                                                  const u16* __restrict__ Wob,
                                                  const float* __restrict__ bo,
                                                  float* __restrict__ out) {
  __shared__ __align__(16) short smem[128 * 32 + 64 * 32];
  const int tid = threadIdx.x;
  const int lane = tid & 63, w = tid >> 6;
  const int l15 = lane & 15, quad = lane >> 4;
  const int m0 = blockIdx.x * 128;
  const int n0 = blockIdx.y * 64;
  short* sA = smem;
  short* sB = smem + 128 * 32;

  const u16* ga = ctx + ((size_t)(m0 + w * 32 + (lane >> 2))) * 1024 +
                  (lane & 3) * 8;
  const u16* gb = Wob + ((size_t)(n0 + w * 16 + (lane >> 2))) * 1024 +
                  (lane & 3) * 8;
  AS3 u32* la = (AS3 u32*)(AS3 short*)sA + w * 512;
  AS3 u32* lb = (AS3 u32*)(AS3 short*)sB + w * 256;

  floatx4 acc[2][4];
#pragma unroll
  for (int i = 0; i < 2; i++)
#pragma unroll
    for (int j = 0; j < 4; j++) acc[i][j] = (floatx4)0.0f;

  for (int kt = 0; kt < 32; ++kt) {
    __syncthreads();
    gld16(ga, la);
    gld16(ga + (size_t)16 * 1024, la + 256);
    gld16(gb, lb);
    ga += 32;
    gb += 32;
    __syncthreads();

    bf16x8 af[2], bfr[4];
#pragma unroll
    for (int mc = 0; mc < 2; ++mc)
      af[mc] = *(const bf16x8*)&sA[(w * 32 + mc * 16 + l15) * 32 + quad * 8];
#pragma unroll
    for (int nc = 0; nc < 4; ++nc)
      bfr[nc] = *(const bf16x8*)&sB[(nc * 16 + l15) * 32 + quad * 8];
#pragma unroll
    for (int mc = 0; mc < 2; ++mc)
#pragma unroll
      for (int nc = 0; nc < 4; ++nc)
        acc[mc][nc] = __builtin_amdgcn_mfma_f32_16x16x32_bf16(
            af[mc], bfr[nc], acc[mc][nc], 0, 0, 0);
  }

#pragma unroll
  for (int mc = 0; mc < 2; ++mc)
#pragma unroll
    for (int nc = 0; nc < 4; ++nc) {
      const int n = n0 + nc * 16 + l15;
      const float bias = bo[n];
#pragma unroll
      for (int r = 0; r < 4; ++r) {
        const int m = m0 + w * 32 + mc * 16 + quad * 4 + r;
        out[(size_t)m * 1024 + n] = acc[mc][nc][r] + bias;
      }
    }
}

// ============ Fallback f32-staging 128x128 GEMM (round-12, verified) ========
template <bool F32A>
__device__ __forceinline__ void gemm128(const void* __restrict__ A,
                                        const float* __restrict__ B, short* sA,
                                        short* sB, floatx4 acc[4][4]) {
  const int tid = threadIdx.x;
  const int lane = tid & 63;
  const int w = tid >> 6;
  const int l15 = lane & 15, quad = lane >> 4;
  const int wm = w >> 1, wn = w & 1;
  const int srow = tid >> 1;
  const int scb = (tid & 1) * 16;

  float4 pa[4], pb[4];
  int4 pa16[2];
  if constexpr (F32A) {
    const float* ap = (const float*)A + (size_t)srow * 1024 + scb;
    pa[0] = ((const float4*)ap)[0]; pa[1] = ((const float4*)ap)[1];
    pa[2] = ((const float4*)ap)[2]; pa[3] = ((const float4*)ap)[3];
  } else {
    const u16* ap = (const u16*)A + (size_t)srow * 1024 + scb;
    pa16[0] = ((const int4*)ap)[0]; pa16[1] = ((const int4*)ap)[1];
  }
  {
    const float* bp = B + (size_t)srow * 1024 + scb;
    pb[0] = ((const float4*)bp)[0]; pb[1] = ((const float4*)bp)[1];
    pb[2] = ((const float4*)bp)[2]; pb[3] = ((const float4*)bp)[3];
  }

  for (int kt = 0; kt < 32; ++kt) {
    __syncthreads();
    if constexpr (F32A) {
      *(bf16x8*)&sA[srow * 40 + scb] = cvt8(pa[0], pa[1]);
      *(bf16x8*)&sA[srow * 40 + scb + 8] = cvt8(pa[2], pa[3]);
    } else {
      *(int4*)&sA[srow * 40 + scb] = pa16[0];
      *(int4*)&sA[srow * 40 + scb + 8] = pa16[1];
    }
    *(bf16x8*)&sB[srow * 40 + scb] = cvt8(pb[0], pb[1]);
    *(bf16x8*)&sB[srow * 40 + scb + 8] = cvt8(pb[2], pb[3]);
    __syncthreads();

    if (kt < 31) {
      const int k0 = (kt + 1) * 32;
      if constexpr (F32A) {
        const float* ap = (const float*)A + (size_t)srow * 1024 + k0 + scb;
        pa[0] = ((const float4*)ap)[0]; pa[1] = ((const float4*)ap)[1];
        pa[2] = ((const float4*)ap)[2]; pa[3] = ((const float4*)ap)[3];
      } else {
        const u16* ap = (const u16*)A + (size_t)srow * 1024 + k0 + scb;
        pa16[0] = ((const int4*)ap)[0]; pa16[1] = ((const int4*)ap)[1];
      }
      const float* bp = B + (size_t)srow * 1024 + k0 + scb;
      pb[0] = ((const float4*)bp)[0]; pb[1] = ((const float4*)bp)[1];
      pb[2] = ((const float4*)bp)[2]; pb[3] = ((const float4*)bp)[3];
    }

    bf16x8 af[4], bfr[4];
#pragma unroll
    for (int mc = 0; mc < 4; ++mc)
      af[mc] = *(const bf16x8*)&sA[(wm * 64 + mc * 16 + l15) * 40 + quad * 8];
#pragma unroll
    for (int nc = 0; nc < 4; ++nc)
      bfr[nc] = *(const bf16x8*)&sB[(wn * 64 + nc * 16 + l15) * 40 + quad * 8];
#pragma unroll
    for (int mc = 0; mc < 4; ++mc)
#pragma unroll
      for (int nc = 0; nc < 4; ++nc)
        acc[mc][nc] = __builtin_amdgcn_mfma_f32_16x16x32_bf16(
            af[mc], bfr[nc], acc[mc][nc], 0, 0, 0);
  }
}

__global__ __launch_bounds__(256) void qkv_gemm_f(
    const float* __restrict__ x, const float* __restrict__ Wq,
    const float* __restrict__ Wk, const float* __restrict__ Wv,
    u16* __restrict__ Q, u16* __restrict__ K, u16* __restrict__ Vt) {
  __shared__ __align__(16) short smem[2 * 128 * 40];
  const int m0 = blockIdx.x * 128;
  const int by = blockIdx.y;
  const int sel = by >> 3;
  const int nb = (by & 7) * 128;
  const float* W = (sel == 0) ? Wq : (sel == 1) ? Wk : Wv;

  floatx4 acc[4][4];
#pragma unroll
  for (int i = 0; i < 4; i++)
#pragma unroll
    for (int j = 0; j < 4; j++) acc[i][j] = (floatx4)0.0f;
  gemm128<true>((const void*)(x + (size_t)m0 * 1024), W + (size_t)nb * 1024,
                smem, smem + 128 * 40, acc);
  qkv_epilogue(acc, m0, nb, sel, Q, K, Vt);
}

__global__ __launch_bounds__(256) void out_gemm_f(const u16* __restrict__ ctx,
                                                  const float* __restrict__ Wo,
                                                  const float* __restrict__ bo,
                                                  float* __restrict__ out) {
  __shared__ __align__(16) short smem[2 * 128 * 40];
  const int tid = threadIdx.x;
  const int lane = tid & 63, w = tid >> 6;
  const int l15 = lane & 15, quad = lane >> 4;
  const int wm = w >> 1, wn = w & 1;
  const int m0 = blockIdx.x * 128;
  const int n0 = blockIdx.y * 128;

  floatx4 acc[4][4];
#pragma unroll
  for (int i = 0; i < 4; i++)
#pragma unroll
    for (int j = 0; j < 4; j++) acc[i][j] = (floatx4)0.0f;
  gemm128<false>((const void*)(ctx + (size_t)m0 * 1024),
                 Wo + (size_t)n0 * 1024, smem, smem + 128 * 40, acc);

#pragma unroll
  for (int mc = 0; mc < 4; ++mc)
#pragma unroll
    for (int nc = 0; nc < 4; ++nc) {
      const int n = n0 + wn * 64 + nc * 16 + l15;
      const float bias = bo[n];
#pragma unroll
      for (int r = 0; r < 4; ++r) {
        const int m = m0 + wm * 64 + mc * 16 + quad * 4 + r;
        out[(size_t)m * 1024 + n] = acc[mc][nc][r] + bias;
      }
    }
}

// ======== per-chunk attention tile (R3/R5 verified paths, no setprio) =======
// CLEAN=true : full 128-key tile, no masks, 2-deep SW pipeline.
// CLEAN=false: diagonal tile with per-kp break + causal masks.
template <bool CLEAN>
__device__ __forceinline__ void attn_tile(const u16* __restrict__ sKb,
                                          const u16* __restrict__ sVb,
                                          const int l15, const int quad,
                                          const int jbase, const int wrow,
                                          const bf16x8 aQ0, const bf16x8 aQ1,
                                          floatx4 (&acc)[4], floatx4& lsv) {
  if constexpr (CLEAN) {
    bf16x8 ka[2][4];
    uint2 va[2][8];
#pragma unroll
    for (int u = 0; u < 4; ++u) {
      const u16* kp0 = sKb + l15 * 72 + quad * 8;
      ka[0][u] = *(const bf16x8*)(kp0 + (u >> 1) * (16 * 72) + (u & 1) * 32);
    }
#pragma unroll
    for (int dt = 0; dt < 4; ++dt) {
      const u16* vp = sVb + (dt * 16 + l15) * 136 + quad * 4;
      va[0][2 * dt] = *(const uint2*)(vp);
      va[0][2 * dt + 1] = *(const uint2*)(vp + 16);
    }
#pragma unroll
    for (int kp = 0; kp < 4; ++kp) {
      const int pc = kp & 1, pn = (kp + 1) & 1;
      if (kp < 3) {
        const u16* kp1 = sKb + ((kp + 1) * 32 + l15) * 72 + quad * 8;
#pragma unroll
        for (int u = 0; u < 4; ++u)
          ka[pn][u] =
              *(const bf16x8*)(kp1 + (u >> 1) * (16 * 72) + (u & 1) * 32);
#pragma unroll
        for (int dt = 0; dt < 4; ++dt) {
          const u16* vp =
              sVb + (dt * 16 + l15) * 136 + (kp + 1) * 32 + quad * 4;
          va[pn][2 * dt] = *(const uint2*)(vp);
          va[pn][2 * dt + 1] = *(const uint2*)(vp + 16);
        }
      }
      floatx4 st0 = (floatx4)0.0f, st1 = (floatx4)0.0f;
      st0 = __builtin_amdgcn_mfma_f32_16x16x32_bf16(ka[pc][0], aQ0, st0, 0, 0,
                                                    0);
      st1 = __builtin_amdgcn_mfma_f32_16x16x32_bf16(ka[pc][2], aQ0, st1, 0, 0,
                                                    0);
      st0 = __builtin_amdgcn_mfma_f32_16x16x32_bf16(ka[pc][1], aQ1, st0, 0, 0,
                                                    0);
      st1 = __builtin_amdgcn_mfma_f32_16x16x32_bf16(ka[pc][3], aQ1, st1, 0, 0,
                                                    0);
      float p0[4], p1[4];
#pragma unroll
      for (int r = 0; r < 4; ++r) {
        p0[r] = __builtin_amdgcn_exp2f(st0[r] - QSHIFT);
        p1[r] = __builtin_amdgcn_exp2f(st1[r] - QSHIFT);
      }
#pragma unroll
      for (int r = 0; r < 4; ++r) lsv[r] += p0[r] + p1[r];
      uint4 pfu{pk2(p0[0], p0[1]), pk2(p0[2], p0[3]), pk2(p1[0], p1[1]),
                pk2(p1[2], p1[3])};
      const bf16x8 pf8 = __builtin_bit_cast(bf16x8, pfu);
#pragma unroll
      for (int dt = 0; dt < 4; ++dt) {
        uint4 avu{va[pc][2 * dt].x, va[pc][2 * dt].y, va[pc][2 * dt + 1].x,
                  va[pc][2 * dt + 1].y};
        bf16x8 av8 = __builtin_bit_cast(bf16x8, avu);
        acc[dt] = __builtin_amdgcn_mfma_f32_16x16x32_bf16(av8, pf8, acc[dt],
                                                          0, 0, 0);
      }
    }
  } else {
#pragma unroll 2
    for (int kp = 0; kp < 4; ++kp) {
      const int kbase = jbase + kp * 32;
      if (kbase > wrow + 15) break;  // wave-uniform

      const u16* kr0 = sKb + (kp * 32 + l15) * 72 + quad * 8;
      bf16x8 ak00 = *(const bf16x8*)(kr0);
      bf16x8 ak01 = *(const bf16x8*)(kr0 + 32);
      floatx4 st0 = (floatx4)0.0f;
      st0 = __builtin_amdgcn_mfma_f32_16x16x32_bf16(ak00, aQ0, st0, 0, 0, 0);
      st0 = __builtin_amdgcn_mfma_f32_16x16x32_bf16(ak01, aQ1, st0, 0, 0, 0);

      const bool have1 = (kbase + 16 <= wrow + 15);  // wave-uniform
      floatx4 st1 = (floatx4)0.0f;
      if (have1) {
        const u16* kr1 = kr0 + 16 * 72;
        bf16x8 ak10 = *(const bf16x8*)(kr1);
        bf16x8 ak11 = *(const bf16x8*)(kr1 + 32);
        st1 = __builtin_amdgcn_mfma_f32_16x16x32_bf16(ak10, aQ0, st1, 0, 0, 0);
        st1 = __builtin_amdgcn_mfma_f32_16x16x32_bf16(ak11, aQ1, st1, 0, 0, 0);
      }

      float p0[4], p1[4];
      const bool m0b = (kbase + 15 > wrow);
#pragma unroll
      for (int r = 0; r < 4; ++r) {
        float t = st0[r] - QSHIFT;
        if (m0b && (kbase + quad * 4 + r > wrow + l15)) t = -1e30f;
        p0[r] = __builtin_amdgcn_exp2f(t);
      }
      if (have1) {
        const bool m1b = (kbase + 31 > wrow);
#pragma unroll
        for (int r = 0; r < 4; ++r) {
          float t = st1[r] - QSHIFT;
          if (m1b && (kbase + 16 + quad * 4 + r > wrow + l15)) t = -1e30f;
          p1[r] = __builtin_amdgcn_exp2f(t);
        }
      } else {
        p1[0] = p1[1] = p1[2] = p1[3] = 0.0f;
      }
#pragma unroll
      for (int r = 0; r < 4; ++r) lsv[r] += p0[r] + p1[r];

      uint4 pfu{pk2(p0[0], p0[1]), pk2(p0[2], p0[3]), pk2(p1[0], p1[1]),
                pk2(p1[2], p1[3])};
      const bf16x8 pf8 = __builtin_bit_cast(bf16x8, pfu);

#pragma unroll
      for (int dt = 0; dt < 4; ++dt) {
        const u16* vp = sVb + (dt * 16 + l15) * 136 + kp * 32 + quad * 4;
        uint2 v0 = *(const uint2*)(vp);
        uint2 v1 = *(const uint2*)(vp + 16);  // p1=0 past diagonal
        uint4 avu{v0.x, v0.y, v1.x, v1.y};
        bf16x8 av8 = __builtin_bit_cast(bf16x8, avu);
        acc[dt] = __builtin_amdgcn_mfma_f32_16x16x32_bf16(av8, pf8, acc[dt],
                                                          0, 0, 0);
      }
    }
  }
}

// --------- per-chunk output write (round-3 epilogue, parameterized) ---------
__device__ __forceinline__ void attn_write(u16* tw, const floatx4 (&acc)[4],
                                           const floatx4 lsv, const int l15,
                                           const int quad, const int wrow,
                                           const int b, const int h,
                                           u16* __restrict__ ctx) {
  float lsum = (lsv[0] + lsv[1]) + (lsv[2] + lsv[3]);
  lsum += __shfl_xor(lsum, 16, 64);
  lsum += __shfl_xor(lsum, 32, 64);
  const float inv = 1.0f / lsum;
#pragma unroll
  for (int dt = 0; dt < 4; ++dt) {
    uint2 o2{pk2(acc[dt][0] * inv, acc[dt][1] * inv),
             pk2(acc[dt][2] * inv, acc[dt][3] * inv)};
    *(uint2*)&tw[l15 * 72 + dt * 16 + quad * 4] = o2;
  }
  // in-wave write->read DS ordering (wave-exclusive region)
  bf16x8 o0 = *(const bf16x8*)&tw[l15 * 72 + quad * 16];
  bf16x8 o1 = *(const bf16x8*)&tw[l15 * 72 + quad * 16 + 8];
  u16* cp =
      ctx + ((size_t)(b * 2048 + wrow + l15)) * 1024 + h * 64 + quad * 16;
  *(bf16x8*)cp = o0;
  *(bf16x8*)(cp + 8) = o1;
}

// ====== Kernel: causal flash attention (dual-chunk shared K/V stream) =======
// R5/R11 structure verbatim (verified optimum: attn ~60us): 256 blocks =
// 8 pairs x 32 bh (bid&31 = bh keeps XCD affinity; 1 block/CU). Chunks
// A=15-pr and B=pr (128 q each, SAME bh) share one tile loop 0..cA; per
// staged tile the verified R3 tile function runs for A and (while jb<=cB)
// for B. Compute units/block = 17 for every pr (balanced); staged tiles
// 16-pr. Double-buffered LDS, 1 barrier/tile; fixed-shift softmax;
// Q pre-scaled by 0.125*log2e.
__global__ __launch_bounds__(512, 2) void attn_kernel(
    const u16* __restrict__ Q, const u16* __restrict__ K,
    const u16* __restrict__ Vt, u16* __restrict__ ctx) {
  const int bid = blockIdx.x;
  const int pr = bid >> 5;  // pair index 0..7
  const int bh = bid & 31;
  const int tid = threadIdx.x;
  const int w = tid >> 6;  // 0..7
  const int lane = tid & 63;
  const int l15 = lane & 15;
  const int quad = lane >> 4;

  constexpr int KE = 128 * 72;  // u16 elems of K region
  constexpr int VE = 64 * 136;  // u16 elems of V region
  constexpr int BUF = KE + VE;  // 35840 B per buffer
  __shared__ __align__(16) u16 lds[2 * BUF];

  const int kr = tid >> 2, kc = (tid & 3) * 16;  // K staging (512 thr)
  const int vd = tid >> 3, vc = (tid & 7) * 16;  // V staging
  const int b = bh >> 4, h = bh & 15;

  const u16* Kg = K + (size_t)bh * 2048 * 64;
  const u16* Vg = Vt + (size_t)bh * 64 * 2048;

  const int cA = 15 - pr, cB = pr;
  const int wrowA = cA * 128 + w * 16;
  const int wrowB = cB * 128 + w * 16;

  // Q fragments for both chunks (same bh)
  bf16x8 aQA0, aQA1, aQB0, aQB1;
  {
    const u16* qa = Q + ((size_t)bh * 2048 + wrowA + l15) * 64 + quad * 8;
    aQA0 = *(const bf16x8*)(qa);
    aQA1 = *(const bf16x8*)(qa + 32);
    const u16* qb = Q + ((size_t)bh * 2048 + wrowB + l15) * 64 + quad * 8;
    aQB0 = *(const bf16x8*)(qb);
    aQB1 = *(const bf16x8*)(qb + 32);
  }

  floatx4 accA[4], accB[4];
#pragma unroll
  for (int i = 0; i < 4; ++i) {
    accA[i] = (floatx4)0.0f;
    accB[i] = (floatx4)0.0f;
  }
  floatx4 lsvA = (floatx4)0.0f, lsvB = (floatx4)0.0f;

  // prefetch + stage tile 0 into buf0
  int4 pk[2], pv[2];
  pk[0] = *(const int4*)(Kg + (size_t)kr * 64 + kc);
  pk[1] = *(const int4*)(Kg + (size_t)kr * 64 + kc + 8);
  pv[0] = *(const int4*)(Vg + (size_t)vd * 2048 + vc);
  pv[1] = *(const int4*)(Vg + (size_t)vd * 2048 + vc + 8);
  *(int4*)&lds[kr * 72 + kc] = pk[0];
  *(int4*)&lds[kr * 72 + kc + 8] = pk[1];
  *(int4*)&lds[KE + vd * 136 + vc] = pv[0];
  *(int4*)&lds[KE + vd * 136 + vc + 8] = pv[1];
  __syncthreads();
  int cur = 0;

  for (int jb = 0; jb <= cA; ++jb) {
    const u16* sKb = lds + cur * BUF;
    const u16* sVb = sKb + KE;

    // (a) prefetch next tile's globals (lands during tile compute)
    const int jn = (jb < cA) ? (jb + 1) * 128 : -1;
    if (jn >= 0) {
      pk[0] = *(const int4*)(Kg + (size_t)(jn + kr) * 64 + kc);
      pk[1] = *(const int4*)(Kg + (size_t)(jn + kr) * 64 + kc + 8);
      pv[0] = *(const int4*)(Vg + (size_t)vd * 2048 + jn + vc);
      pv[1] = *(const int4*)(Vg + (size_t)vd * 2048 + jn + vc + 8);
    }

    // (b) compute tile jb from buf[cur]: chunk A, then chunk B if active
    const int jbase = jb * 128;
    if (jb < cA)
      attn_tile<true>(sKb, sVb, l15, quad, jbase, wrowA, aQA0, aQA1, accA,
                      lsvA);
    else
      attn_tile<false>(sKb, sVb, l15, quad, jbase, wrowA, aQA0, aQA1, accA,
                       lsvA);
    if (jb < cB)
      attn_tile<true>(sKb, sVb, l15, quad, jbase, wrowB, aQB0, aQB1, accB,
                      lsvB);
    else if (jb == cB)
      attn_tile<false>(sKb, sVb, l15, quad, jbase, wrowB, aQB0, aQB1, accB,
                       lsvB);

    // (c) stage next tile into buf[cur^1] (retired at last barrier)
    if (jn >= 0) {
      u16* dK = lds + (cur ^ 1) * BUF;
      u16* dV = dK + KE;
      *(int4*)&dK[kr * 72 + kc] = pk[0];
      *(int4*)&dK[kr * 72 + kc + 8] = pk[1];
      *(int4*)&dV[vd * 136 + vc] = pv[0];
      *(int4*)&dV[vd * 136 + vc + 8] = pv[1];
    }
    // (d) one barrier per tile
    __syncthreads();
    cur ^= 1;
  }

  // ---- epilogue: both chunks; per-wave exclusive scratch in retired buf ----
  u16* tw = lds + (cur ^ 1) * BUF + (w * 16) * 72;
  attn_write(tw, accA, lsvA, l15, quad, wrowA, b, h, ctx);
  attn_write(tw, accB, lsvB, l15, quad, wrowB, b, h, ctx);
}

// ============================== launch ======================================
extern "C" void kernel_launch(void* const* d_in, const int* in_sizes, int n_in,
                              void* d_out, int out_size, void* d_ws,
                              size_t ws_size, hipStream_t stream) {
  const float* x = (const float*)d_in[0];
  const float* Wq = (const float*)d_in[1];
  const float* Wk = (const float*)d_in[2];
  const float* Wv = (const float*)d_in[3];
  const float* Wo = (const float*)d_in[4];
  const float* bo = (const float*)d_in[5];
  float* out = (float*)d_out;

  u16* Q = (u16*)d_ws;                  // 8 MB
  u16* K = Q + (size_t)4096 * 1024;     // 8 MB
  u16* Vt = K + (size_t)4096 * 1024;    // 8 MB
  u16* ctx = Vt + (size_t)4096 * 1024;  // 8 MB (shared slot with xb)

  if (ws_size >= (size_t)40 * 1024 * 1024) {
    u16* xb = ctx;  // xb consumed by qkv before attn writes ctx
    u16* Wqb = (u16*)d_ws + (size_t)16 * 1024 * 1024;  // at 32 MB
    u16* Wkb = Wqb + (size_t)1024 * 1024;
    u16* Wvb = Wkb + (size_t)1024 * 1024;
    u16* Wob = Wvb + (size_t)1024 * 1024;  // ends at 40 MB

    cvt_all<<<4096, 256, 0, stream>>>(x, Wq, Wk, Wv, Wo, xb, Wqb, Wkb, Wvb,
                                      Wob);
    qkv_gemm_b<<<dim3(32, 24), 256, 0, stream>>>(xb, Wqb, Wkb, Wvb, Q, K, Vt);
    attn_kernel<<<256, 512, 0, stream>>>(Q, K, Vt, ctx);
    out_gemm_b<<<dim3(32, 16), 256, 0, stream>>>(ctx, Wob, bo, out);
  } else {
    qkv_gemm_f<<<dim3(32, 24), 256, 0, stream>>>(x, Wq, Wk, Wv, Q, K, Vt);
    attn_kernel<<<256, 512, 0, stream>>>(Q, K, Vt, ctx);
    out_gemm_f<<<dim3(32, 8), 256, 0, stream>>>(ctx, Wo, bo, out);
  }
}